// Round 18
// baseline (232.829 us; speedup 1.0000x reference)
//
#include <hip/hip_runtime.h>
#include <math.h>

// ---------------------------------------------------------------------------
// Model: conv1(5x5,20)+pool2 -> conv2(5x5,50)+pool2 -> pcaps(5x5 pad2,16)
//        -> squash -> priors -> dynamic routing(3) -> fc1(relu) -> fc2
// B=2048. conv1/conv2/pcaps/fc1 via bf16 MFMA (16x16x32).
// R18: (a) k_conv1 grouped im2col: 8 groups x 2 chunks, 224/256 builder
// threads, 16 barriers (was 32). (b) k_conv2p stage: row-per-thread copy
// (no div/mod), pad-zeroing folded in.
// h_bf POSITION-MAJOR: k' = pos*50 + oc, padded to 3712 (=4*928, 928=29*32).
// ---------------------------------------------------------------------------

#define BATCH 2048
#define KP 3712          // padded K for fc1 (4 k-splits x 928, 928 = 29*32)

typedef __attribute__((ext_vector_type(8))) short short8;
typedef __attribute__((ext_vector_type(4))) float floatx4;
typedef unsigned short u16;
typedef unsigned int   u32;

// async global->LDS: HW writes lane i's 16B to (wave-uniform lds base)+i*16
#define GLD(gp, lp) __builtin_amdgcn_global_load_lds( \
    (const __attribute__((address_space(1))) u32*)(gp), \
    (__attribute__((address_space(3))) u32*)(lp), 16, 0, 0)

__device__ inline float wave_sum(float v) {
#pragma unroll
    for (int off = 32; off >= 1; off >>= 1) v += __shfl_xor(v, off);
    return v;
}
__device__ inline float wave_max(float v) {
#pragma unroll
    for (int off = 32; off >= 1; off >>= 1) v = fmaxf(v, __shfl_xor(v, off));
    return v;
}
__device__ inline u16 f2bf(float f) {  // RNE fp32->bf16 (finite)
    u32 u = __float_as_uint(f);
    u32 r = (u + 0x7FFFu + ((u >> 16) & 1u)) >> 16;
    return (u16)r;
}

// ---------- Kernel 0: weight conversions -----------------------------------
__global__ __launch_bounds__(256) void k_prep(
    const float* __restrict__ fw,  u16* __restrict__ w_bf,
    const float* __restrict__ w2,  u16* __restrict__ w2t,
    const float* __restrict__ pcw, u16* __restrict__ w_pc,
    const float* __restrict__ w1,  u16* __restrict__ w1t,
    const float* __restrict__ f1b, const float* __restrict__ f2w,
    float* __restrict__ wtab)
{
    __shared__ __align__(16) float srow[3600];
    const int blk = blockIdx.x, t = threadIdx.x;
    if (blk < 500) {
        const int n = blk;
        const float* src = fw + (size_t)n * 3602;
        for (int i = t; i < 1800; i += 256)
            *(float2*)&srow[2 * i] = *(const float2*)&src[2 * i];
        __syncthreads();
        u32* dst = (u32*)(w_bf + (size_t)n * KP);
        for (int i = t; i < 1856; i += 256) {
            int k2 = 2 * i;
            u32 pk = 0u;
            if (k2 < 3600) {
                int pos = k2 / 50, oc = k2 - 50 * pos;
                pk = (u32)f2bf(srow[oc * 72 + pos])
                   | ((u32)f2bf(srow[(oc + 1) * 72 + pos]) << 16);
            }
            dst[i] = pk;
        }
    } else if (blk == 500) {
        u32* z = (u32*)(w_bf + (size_t)500 * KP);
        for (int i = t; i < 22272; i += 256) z[i] = 0u;   // 12 * 1856
    } else if (blk < 526) {
        int g   = (blk - 501) * 256 + t;
        int idx = g * 8;
        int tap = idx >> 11;
        int oc  = (idx >> 5) & 63;
        int ic0 = idx & 31;
        u16 v[8];
#pragma unroll
        for (int j = 0; j < 8; ++j) {
            int ic = ic0 + j;
            float f = (ic < 20 && oc < 50) ? w2[oc * 500 + ic * 25 + tap] : 0.f;
            v[j] = f2bf(f);
        }
        *(short8*)&w2t[idx] = *(short8*)v;
    } else if (blk < 539) {
        int g = (blk - 526) * 256 + t;
        if (g >= 3200) return;
        int idx = g * 8;
        int tap = idx >> 10;
        int rem = idx & 1023;
        int oc  = rem >> 6;
        int ic0 = rem & 63;
        u16 v[8];
#pragma unroll
        for (int j = 0; j < 8; ++j) {
            int ic = ic0 + j;
            float f = (ic < 50) ? pcw[(oc * 50 + ic) * 25 + tap] : 0.f;
            v[j] = f2bf(f);
        }
        *(short8*)&w_pc[idx] = *(short8*)v;
    } else if (blk == 539) {
        if (t < 128) {
            int n  = t >> 2;
            int k0 = (t & 3) * 8;
            u16 v[8];
#pragma unroll
            for (int j = 0; j < 8; ++j) {
                int k = k0 + j;
                float f = (n < 20 && k < 25) ? w1[n * 25 + k] : 0.f;
                v[j] = f2bf(f);
            }
            *(short8*)&w1t[t * 8] = *(short8*)v;
        }
    } else {
        for (int nn = t; nn < 512; nn += 256) {
            float bias = 0.f, wc0 = 0.f, wc1 = 0.f, f20 = 0.f, f21 = 0.f;
            if (nn < 500) {
                bias = f1b[nn];
                wc0  = fw[(size_t)nn * 3602 + 3600];
                wc1  = fw[(size_t)nn * 3602 + 3601];
                f20  = f2w[nn];
                f21  = f2w[502 + nn];
            }
            *(float4*)&wtab[nn * 8]     = make_float4(bias, wc0, wc1, f20);
            *(float4*)&wtab[nn * 8 + 4] = make_float4(f21, 0.f, 0.f, 0.f);
        }
    }
}

// ---------- Kernel 1a: conv1 (grouped MFMA im2col) -> h1g [B][448][20] -----
// LDS: xbf[36][64] @0 (2304 sh) | im2[224][40] @2304 (8960 sh) |
//      h1s[448][20] @11264 (8960 sh)  = 40448 B -> 4 blocks/CU
// 8 groups x 2 chunks: 224 builder threads, 2 barriers/group.
__global__ __launch_bounds__(256, 4) void k_conv1(
    const float* __restrict__ x, const u16* __restrict__ w1t,
    const float* __restrict__ b1, u32* __restrict__ h1g)
{
    __shared__ __align__(16) u16 smem[20224];
    u16* xbf = smem;            // 2304 shorts
    u16* im2 = smem + 2304;     // 8960 shorts [224][40]
    u16* h1s = smem + 11264;    // 8960 shorts [448][20]

    const int t = threadIdx.x;
    const int b = blockIdx.x;

    const float* xb = x + b * 2160;
    for (int i = t; i < 2160; i += 256) {
        int r = i / 60, c = i - 60 * r;
        xbf[r * 64 + c] = f2bf(xb[i]);
    }
    __syncthreads();

    const int lane = t & 63, w = t >> 6;
    const int r16  = lane & 15;
    const int q    = lane >> 4;

    short8 w1f[2];
#pragma unroll
    for (int nt = 0; nt < 2; ++nt)
        w1f[nt] = *(const short8*)&w1t[(nt * 16 + r16) * 32 + q * 8];

    // builder constants: t<224 builds im2 row t (chunk lc=t/112, local pl)
    const bool bact = (t < 224);
    const int lc_  = t / 112;
    const int pl_  = t - 112 * lc_;
    const int px_  = pl_ >> 2;
    const int dy_  = (pl_ & 3) >> 1, dx_ = pl_ & 1;
    const int xc_  = 2 * px_ + dx_;
    const int j0_  = xc_ >> 1;
    const int par_ = xc_ & 1;
    const int sw_  = (t >> 3) & 3;   // swizzle keyed on full im2 row index

#pragma unroll 1
    for (int g = 0; g < 8; ++g) {
        if (bact) {
            int c = 2 * g + lc_;     // chunk = pooled row, 0..15
            u16 tap[25];
#pragma unroll
            for (int r = 0; r < 5; ++r) {
                const u32* U = (const u32*)&xbf[(2 * c + dy_ + r) * 64];
                u32 A0 = U[j0_], A1 = U[j0_ + 1], A2 = U[j0_ + 2];
                u16 e0 = par_ ? (u16)(A0 >> 16) : (u16)A0;
                u16 e1 = par_ ? (u16)A1         : (u16)(A0 >> 16);
                u16 e2 = par_ ? (u16)(A1 >> 16) : (u16)A1;
                u16 e3 = par_ ? (u16)A2         : (u16)(A1 >> 16);
                u16 e4 = par_ ? (u16)(A2 >> 16) : (u16)A2;
                tap[r * 5 + 0] = e0; tap[r * 5 + 1] = e1; tap[r * 5 + 2] = e2;
                tap[r * 5 + 3] = e3; tap[r * 5 + 4] = e4;
            }
            u32 ow[16];
#pragma unroll
            for (int j = 0; j < 12; ++j)
                ow[j] = (u32)tap[2 * j] | ((u32)tap[2 * j + 1] << 16);
            ow[12] = (u32)tap[24];
            ow[13] = 0u; ow[14] = 0u; ow[15] = 0u;
            u32* dst = (u32*)&im2[t * 40];
            *(uint4*)&dst[(0 ^ sw_) * 4] = make_uint4(ow[0],  ow[1],  ow[2],  ow[3]);
            *(uint4*)&dst[(1 ^ sw_) * 4] = make_uint4(ow[4],  ow[5],  ow[6],  ow[7]);
            *(uint4*)&dst[(2 ^ sw_) * 4] = make_uint4(ow[8],  ow[9],  ow[10], ow[11]);
            *(uint4*)&dst[(3 ^ sw_) * 4] = make_uint4(ow[12], ow[13], ow[14], ow[15]);
        }
        __syncthreads();
        // 14 m-tiles: wave w takes mt = w, w+4, w+8, w+12 (<14)
#pragma unroll
        for (int mi = 0; mi < 4; ++mi) {
            int mt = w + 4 * mi;
            if (mt < 14) {
                int m  = mt * 16 + r16;       // im2 row 0..223
                int sr = (m >> 3) & 3;
                short8 af = *(const short8*)&im2[m * 40 + ((q ^ sr) * 8)];
                floatx4 a1[2] = {};
#pragma unroll
                for (int nt = 0; nt < 2; ++nt)
                    a1[nt] = __builtin_amdgcn_mfma_f32_16x16x32_bf16(
                        af, w1f[nt], a1[nt], 0, 0, 0);
                int ci  = mt / 7;
                int mtl = mt - 7 * ci;
                int c   = 2 * g + ci;
                int pq  = mtl * 4 + q;        // pooled col 0..27
#pragma unroll
                for (int nt = 0; nt < 2; ++nt) {
                    int oc = nt * 16 + r16;
                    if (oc < 20) {
                        floatx4 a = a1[nt];
                        float v = fmaxf(fmaxf(a[0], a[1]), fmaxf(a[2], a[3]))
                                + b1[oc];
                        h1s[(c * 28 + pq) * 20 + oc] = f2bf(v);
                    }
                }
            }
        }
        __syncthreads();   // im2 reads done before next group's build
    }

    u32* hg = h1g + (size_t)b * 4480;
    for (int i = t; i < 4480; i += 256) hg[i] = ((u32*)h1s)[i];
}

// ---------- Kernel 1b: conv2 + pool + pack + pcaps + routing ---------------
// LDS 35840 B:
//   conv phase : h1t[448][40] u16 @0 (cols 20..31 zero, 32..39 unread)
//   post phase : hsbuf[176][72] u16 @0; psum f32 @0 overlays; pri @21760 B
__global__ __launch_bounds__(256, 4) void k_conv2p(
    const u32* __restrict__ h1g, const u16* __restrict__ w2t,
    const float* __restrict__ b2, const u16* __restrict__ w_pc,
    const float* __restrict__ pcb, const float* __restrict__ rw,
    u32* __restrict__ h_bf, float* __restrict__ cbuf)
{
    __shared__ __align__(16) u16 smem[17920];   // 35840 B
    u16* h1t = smem;

    const int t = threadIdx.x;
    const int b = blockIdx.x;

    // stage h1g [448][10]u32 -> h1t pitch-20 u32 rows, zero pad cols folded
    {
        const u32* hg = h1g + (size_t)b * 4480;
#pragma unroll 1
        for (int r0 = t; r0 < 448; r0 += 256) {
            const u32* src = hg + r0 * 10;
            u32* dstp = (u32*)h1t + r0 * 20;
            uint2 a0 = *(const uint2*)(src);
            uint2 a1 = *(const uint2*)(src + 2);
            uint2 a2 = *(const uint2*)(src + 4);
            uint2 a3 = *(const uint2*)(src + 6);
            uint2 a4 = *(const uint2*)(src + 8);
            *(uint4*)(dstp)      = make_uint4(a0.x, a0.y, a1.x, a1.y);
            *(uint4*)(dstp + 4)  = make_uint4(a2.x, a2.y, a3.x, a3.y);
            *(uint2*)(dstp + 8)  = a4;
            *(uint4*)(dstp + 10) = make_uint4(0u, 0u, 0u, 0u);   // cols 20-27
            *(uint2*)(dstp + 14) = make_uint2(0u, 0u);           // cols 28-31
        }
    }
    __syncthreads();

    const int lane = t & 63, w = t >> 6;
    const int r16  = lane & 15;
    const int q    = lane >> 4;

    // ---- conv2 via MFMA: M=288 Z-ordered pre-pool, N=64, K=32, 25 taps ----
    int abase[5];
#pragma unroll
    for (int i = 0; i < 5; ++i) {
        int mt = w + 4 * i;
        if (mt < 18) {
            int m  = mt * 16 + r16;
            int pq = m >> 2, sub = m & 3;
            int py = pq / 12, px = pq - py * 12;
            int yy = py * 2 + (sub >> 1);
            int xx = px * 2 + (sub & 1);
            abase[i] = (yy * 28 + xx) * 40 + q * 8;
        } else abase[i] = 0;
    }
    floatx4 acc2[5][4] = {};
    const u16* wtb = w2t + r16 * 32 + q * 8;

    short8 bf[4];
#pragma unroll
    for (int nt = 0; nt < 4; ++nt)
        bf[nt] = *(const short8*)&wtb[nt * 512];

#pragma unroll 1
    for (int tap = 0; tap < 25; ++tap) {
        short8 bfn[4];
        if (tap < 24) {
#pragma unroll
            for (int nt = 0; nt < 4; ++nt)
                bfn[nt] = *(const short8*)&wtb[(tap + 1) * 2048 + nt * 512];
        }
        int r = tap / 5, s = tap - 5 * r;
        int aoff = r * 1120 + s * 40;
#pragma unroll
        for (int i = 0; i < 5; ++i) {
            int mt = w + 4 * i;
            if (mt < 18) {
                short8 af = *(const short8*)&h1t[abase[i] + aoff];
#pragma unroll
                for (int nt = 0; nt < 4; ++nt)
                    acc2[i][nt] = __builtin_amdgcn_mfma_f32_16x16x32_bf16(
                        af, bf[nt], acc2[i][nt], 0, 0, 0);
            }
        }
#pragma unroll
        for (int nt = 0; nt < 4; ++nt) bf[nt] = bfn[nt];
    }
    __syncthreads();  // all h1t reads done; smem repurposed as hsbuf

    // ---- zero hsbuf [176][72] u16 ----
    for (int i = t; i < 6336; i += 256) ((u32*)smem)[i] = 0u;
    __syncthreads();

    // ---- pool: write f2bf(pooled) DIRECTLY into hsbuf interior ----
    u16* hsbuf = smem;
#pragma unroll
    for (int i = 0; i < 5; ++i) {
        int mt = w + 4 * i;
        if (mt < 18) {
            int pq = mt * 4 + q;   // pos 0..71
            int ph = pq / 12, pw = pq - 12 * ph;
#pragma unroll
            for (int nt = 0; nt < 4; ++nt) {
                int oc = nt * 16 + r16;
                if (oc < 50) {
                    floatx4 a = acc2[i][nt];
                    float v = fmaxf(fmaxf(a[0], a[1]), fmaxf(a[2], a[3])) + b2[oc];
                    hsbuf[((ph + 2) * 16 + pw + 2) * 72 + oc] = f2bf(v);
                }
            }
        }
    }
    __syncthreads();

    // ---- pack h_bf (global) from hsbuf; then pcaps MFMA ----
    u32* ho = h_bf + (size_t)b * 1856;
    for (int i = t; i < 1856; i += 256) {
        u32 pk = 0u;
        if (i < 1800) {
            int k2 = 2 * i;
            int pos = k2 / 50;
            int oc  = k2 - 50 * pos;      // even
            int ph  = pos / 12, pw = pos - 12 * ph;
            pk = ((const u32*)hsbuf)[((((ph + 2) * 16) + pw + 2) * 72 + oc) >> 1];
        }
        ho[i] = pk;
    }

    int pbase[5];
#pragma unroll
    for (int mt = 0; mt < 5; ++mt) {
        int m  = mt * 16 + r16;
        int ph = m / 12, pw = m - 12 * ph;
        pbase[mt] = (ph * 16 + pw) * 72 + q * 8;
    }
    floatx4 pacc[5] = {};
    const u16* wp = w_pc + r16 * 64 + q * 8;
    const int ntap = (28 - w) >> 2;
#pragma unroll 1
    for (int tt = 0; tt < ntap; ++tt) {
        int tap = w + 4 * tt;
        short8 b0 = *(const short8*)&wp[tap * 1024];
        short8 b1 = *(const short8*)&wp[tap * 1024 + 32];
        int r = tap / 5, s = tap - 5 * r;
        int aoff = (r * 16 + s) * 72;
#pragma unroll
        for (int mt = 0; mt < 5; ++mt) {
            short8 a0 = *(const short8*)&hsbuf[pbase[mt] + aoff];
            short8 a1 = *(const short8*)&hsbuf[pbase[mt] + aoff + 32];
            pacc[mt] = __builtin_amdgcn_mfma_f32_16x16x32_bf16(a0, b0, pacc[mt], 0, 0, 0);
            pacc[mt] = __builtin_amdgcn_mfma_f32_16x16x32_bf16(a1, b1, pacc[mt], 0, 0, 0);
        }
    }
    __syncthreads();  // hsbuf reads done -> overlay psum @0

    float* psum = (float*)smem;  // [4][80*17] f32 = 21760 B
#pragma unroll
    for (int mt = 0; mt < 5; ++mt)
#pragma unroll
        for (int i = 0; i < 4; ++i) {
            int m = mt * 16 + q * 4 + i;
            psum[w * 1360 + m * 17 + r16] = pacc[mt][i];
        }
    __syncthreads();

    for (int i = t; i < 1152; i += 256) {
        int m = i >> 4, oc = i & 15;
        int a = m * 17 + oc;
        float s = psum[a] + psum[1360 + a] + psum[2720 + a] + psum[4080 + a]
                + pcb[oc];
        psum[a] = s;
    }
    __syncthreads();

    // squash + priors -> pri @ byte 21760
    float* pri = (float*)(smem + 10880);
    for (int r = t; r < 288; r += 256) {
        int sub = r / 72;
        int pos = r - sub * 72;
        float u0 = psum[pos * 17 + 0  + sub];
        float u1 = psum[pos * 17 + 4  + sub];
        float u2 = psum[pos * 17 + 8  + sub];
        float u3 = psum[pos * 17 + 12 + sub];
        float n2 = u0 * u0 + u1 * u1 + u2 * u2 + u3 * u3;
        float scale = (n2 / (1.0f + n2)) * rsqrtf(n2);
        u0 *= scale; u1 *= scale; u2 *= scale; u3 *= scale;
#pragma unroll
        for (int k = 0; k < 2; ++k) {
            const float4 wv = *(const float4*)&rw[(k * 288 + r) * 4];
            pri[k * 288 + r] = u0 * wv.x + u1 * wv.y + u2 * wv.z + u3 * wv.w;
        }
    }
    __syncthreads();

    // dynamic routing (3 iters): wave 0 -> k=0, wave 1 -> k=1
    if (w < 2) {
        const float* pr = &pri[w * 288];
        float p[5];
        bool  val[5];
#pragma unroll
        for (int j = 0; j < 5; ++j) {
            int r  = j * 64 + lane;
            val[j] = r < 288;
            p[j]   = val[j] ? pr[r] : 0.0f;
        }
        float tot = wave_sum(p[0] + p[1] + p[2] + p[3] + p[4]);
        float s = tot * (1.0f / 288.0f);
        float a = s * fabsf(s) / (1.0f + s * s);
#pragma unroll
        for (int it = 0; it < 2; ++it) {
            float l[5];
            float lm = -INFINITY;
#pragma unroll
            for (int j = 0; j < 5; ++j) {
                l[j] = val[j] ? p[j] * a : -INFINITY;
                lm   = fmaxf(lm, l[j]);
            }
            lm = wave_max(lm);
            float se = 0.f, sp = 0.f;
#pragma unroll
            for (int j = 0; j < 5; ++j) {
                float e = val[j] ? expf(l[j] - lm) : 0.f;
                se += e;
                sp += e * p[j];
            }
            se = wave_sum(se);
            sp = wave_sum(sp);
            float sv = sp / se;
            float v  = sv * fabsf(sv) / (1.0f + sv * sv);
            if (it == 0) a += v;
            else if (lane == 0) cbuf[b * 2 + w] = v;
        }
    }
}

// ---------- Kernel 2: fc1 partial GEMM (m-split, GLD staging) --------------
__global__ __launch_bounds__(256) void k_fc1(
    const u16* __restrict__ h_bf, const u16* __restrict__ w_bf,
    float* __restrict__ f1buf)
{
    __shared__ __align__(16) u16 As[64 * 32];    // 4096 B
    __shared__ __align__(16) u16 Bs[64 * 32];    // 4096 B
    const int t = threadIdx.x;
    const int lane = t & 63, w = t >> 6;
    const int m0 = blockIdx.x * 64;
    const int n0 = blockIdx.y * 64;
    const int s  = blockIdx.z;
    const int k0 = s * 928;

    const u16* ga = h_bf + (size_t)(m0 + (t >> 2)) * KP + k0 + (t & 3) * 8;
    const u16* gb = w_bf + (size_t)(n0 + (t >> 2)) * KP + k0 + (t & 3) * 8;
    u16* lA = As + w * 512;
    u16* lB = Bs + w * 512;

    const int r16 = lane & 15, q = lane >> 4;
    const int ar = (w * 16 + r16) * 32 + q * 8;
    const int br = r16 * 32 + q * 8;

    floatx4 acc[4] = {};
#pragma unroll 1
    for (int it = 0; it < 29; ++it) {
        const int ko = it * 32;
        GLD(ga + ko, lA);
        GLD(gb + ko, lB);
        __syncthreads();
        short8 af = *(const short8*)&As[ar];
#pragma unroll
        for (int nt = 0; nt < 4; ++nt) {
            short8 bfv = *(const short8*)&Bs[br + nt * 512];
            acc[nt] = __builtin_amdgcn_mfma_f32_16x16x32_bf16(af, bfv, acc[nt], 0, 0, 0);
        }
        __syncthreads();
    }

    float* fo = f1buf + (size_t)s * (2048 * 512);
    const int mb = m0 + w * 16;
#pragma unroll
    for (int nt = 0; nt < 4; ++nt) {
        int n = n0 + nt * 16 + r16;
#pragma unroll
        for (int i = 0; i < 4; ++i) {
            int m = mb + q * 4 + i;
            fo[(size_t)m * 512 + n] = acc[nt][i];
        }
    }
}

// ---------- Kernel 3: fc2 final — sum partials, relu, dot ------------------
__global__ __launch_bounds__(256) void k_fc2(
    const float* __restrict__ f1buf, const float* __restrict__ wtab,
    const float* __restrict__ cc, const float* __restrict__ y,
    const float* __restrict__ f2w, const float* __restrict__ f2b,
    float* __restrict__ out)
{
    const int b = blockIdx.x * 4 + (threadIdx.x >> 6);
    const int lane = threadIdx.x & 63;
    const float* fb = f1buf + (size_t)b * 512;
    const float c0 = cc[b * 2], c1 = cc[b * 2 + 1];
    float s0 = 0.f, s1 = 0.f;
#pragma unroll
    for (int j = 0; j < 8; ++j) {
        int n = lane + j * 64;
        float raw = fb[n] + fb[1048576 + n] + fb[2097152 + n] + fb[3145728 + n];
        float4 t0 = *(const float4*)&wtab[n * 8];
        float  f21 = wtab[n * 8 + 4];
        float v = fmaxf(raw + t0.x + c0 * t0.y + c1 * t0.z, 0.f);
        s0 += v * t0.w;
        s1 += v * f21;
    }
    s0 = wave_sum(s0);
    s1 = wave_sum(s1);
    if (lane == 0) {
        float y0 = y[b * 2], y1 = y[b * 2 + 1];
        out[b * 2]     = s0 + f2b[0] + y0 * f2w[500] + y1 * f2w[501];
        out[b * 2 + 1] = s1 + f2b[1] + y0 * f2w[1002] + y1 * f2w[1003];
    }
}

// ---------------------------------------------------------------------------
extern "C" void kernel_launch(void* const* d_in, const int* in_sizes, int n_in,
                              void* d_out, int out_size, void* d_ws, size_t ws_size,
                              hipStream_t stream) {
    const float* x    = (const float*)d_in[0];
    const float* y    = (const float*)d_in[1];
    const float* c1w  = (const float*)d_in[2];
    const float* c1b  = (const float*)d_in[3];
    const float* c2w  = (const float*)d_in[4];
    const float* c2b  = (const float*)d_in[5];
    const float* pcw  = (const float*)d_in[6];
    const float* pcb  = (const float*)d_in[7];
    const float* rw   = (const float*)d_in[8];
    const float* f1w  = (const float*)d_in[9];
    const float* f1b  = (const float*)d_in[10];
    const float* f2w  = (const float*)d_in[11];
    const float* f2b  = (const float*)d_in[12];
    float* out = (float*)d_out;

    // workspace layout (~56 MB peak; h1g overlaps f1buf — h1g fully consumed
    // by k_conv2p before k_fc1 writes f1buf, stream-ordered)
    u32*   h_bf  = (u32*)d_ws;                            // 2048*1856 u32
    u16*   w_bf  = (u16*)(h_bf + (size_t)BATCH * 1856);   // 512*3712 u16
    u16*   w2t   = w_bf + (size_t)512 * KP;               // 25*64*32 u16
    u16*   w_pc  = w2t + 51200;                           // 25*16*64 u16
    u16*   w1t   = w_pc + 25600;                          // 32*32 u16
    float* cbuf  = (float*)(w1t + 1024);                  // 4096 f32
    float* wtab  = cbuf + 4096;                           // 4096 f32
    float* f1buf = wtab + 4096;                           // 4*2048*512 f32
    u32*   h1g   = (u32*)f1buf;                           // 2048*4480 u32 (overlap)

    k_prep<<<541, 256, 0, stream>>>(f1w, w_bf, c2w, w2t, pcw, w_pc, c1w, w1t,
                                    f1b, f2w, wtab);
    k_conv1<<<BATCH, 256, 0, stream>>>(x, w1t, c1b, h1g);
    k_conv2p<<<BATCH, 256, 0, stream>>>(h1g, w2t, c2b, w_pc, pcb, rw,
                                        h_bf, cbuf);
    dim3 g4(32, 8, 4);
    k_fc1<<<g4, 256, 0, stream>>>((const u16*)h_bf, w_bf, f1buf);
    k_fc2<<<BATCH / 4, 256, 0, stream>>>(f1buf, wtab, cbuf, y, f2w, f2b, out);
}

// Round 19
// 229.085 us; speedup vs baseline: 1.0163x; 1.0163x over previous
//
#include <hip/hip_runtime.h>
#include <math.h>

// ---------------------------------------------------------------------------
// Model: conv1(5x5,20)+pool2 -> conv2(5x5,50)+pool2 -> pcaps(5x5 pad2,16)
//        -> squash -> priors -> dynamic routing(3) -> fc1(relu) -> fc2
// B=2048. conv1/conv2/pcaps/fc1 via bf16 MFMA (16x16x32).
// R19: k_prep folded into k_conv1's grid (blocks >= 2048 do weight conversion;
// conv blocks convert w1 inline from float). Launches 5 -> 4.
// h_bf POSITION-MAJOR: k' = pos*50 + oc, padded to 3712 (=4*928, 928=29*32).
// ---------------------------------------------------------------------------

#define BATCH 2048
#define KP 3712          // padded K for fc1 (4 k-splits x 928, 928 = 29*32)
#define NPREP 551        // 512 w_bf rows + 25 w2t + 13 w_pc + 1 wtab

typedef __attribute__((ext_vector_type(8))) short short8;
typedef __attribute__((ext_vector_type(4))) float floatx4;
typedef unsigned short u16;
typedef unsigned int   u32;

// async global->LDS: HW writes lane i's 16B to (wave-uniform lds base)+i*16
#define GLD(gp, lp) __builtin_amdgcn_global_load_lds( \
    (const __attribute__((address_space(1))) u32*)(gp), \
    (__attribute__((address_space(3))) u32*)(lp), 16, 0, 0)

__device__ inline float wave_sum(float v) {
#pragma unroll
    for (int off = 32; off >= 1; off >>= 1) v += __shfl_xor(v, off);
    return v;
}
__device__ inline float wave_max(float v) {
#pragma unroll
    for (int off = 32; off >= 1; off >>= 1) v = fmaxf(v, __shfl_xor(v, off));
    return v;
}
__device__ inline u16 f2bf(float f) {  // RNE fp32->bf16 (finite)
    u32 u = __float_as_uint(f);
    u32 r = (u + 0x7FFFu + ((u >> 16) & 1u)) >> 16;
    return (u16)r;
}

// ---------- Kernel 1a: conv1 (grouped MFMA im2col) + fused weight prep -----
// conv blocks (bx<2048): LDS xbf[36][64]@0 | im2[224][40]@2304 |
//   h1s[448][20]@11264 = 40448 B. prep blocks (bx>=2048): srow overlay.
__global__ __launch_bounds__(256, 4) void k_conv1(
    const float* __restrict__ x, const float* __restrict__ w1,
    const float* __restrict__ b1, u32* __restrict__ h1g,
    const float* __restrict__ fw,  u16* __restrict__ w_bf,
    const float* __restrict__ w2,  u16* __restrict__ w2t,
    const float* __restrict__ pcw, u16* __restrict__ w_pc,
    const float* __restrict__ f1b, const float* __restrict__ f2w,
    float* __restrict__ wtab)
{
    __shared__ __align__(16) u16 smem[20224];
    const int t  = threadIdx.x;
    const int bx = blockIdx.x;

    if (bx >= BATCH) {
        // ---------------- prep branch ----------------
        const int blk = bx - BATCH;
        if (blk < 512) {
            // fc1 weights row n -> w_bf[n][KP] bf16, K-permuted (rows>=500 zero)
            float* srow = (float*)smem;   // 3600 f32 = 14400 B
            const int n = blk;
            if (n < 500) {
                const float* src = fw + (size_t)n * 3602;
                for (int i = t; i < 1800; i += 256)
                    *(float2*)&srow[2 * i] = *(const float2*)&src[2 * i];
            }
            __syncthreads();
            u32* dst = (u32*)(w_bf + (size_t)n * KP);
            for (int i = t; i < 1856; i += 256) {
                int k2 = 2 * i;
                u32 pk = 0u;
                if (n < 500 && k2 < 3600) {
                    int pos = k2 / 50, oc = k2 - 50 * pos;
                    pk = (u32)f2bf(srow[oc * 72 + pos])
                       | ((u32)f2bf(srow[(oc + 1) * 72 + pos]) << 16);
                }
                dst[i] = pk;
            }
        } else if (blk < 537) {
            int g   = (blk - 512) * 256 + t;
            int idx = g * 8;
            int tap = idx >> 11;
            int oc  = (idx >> 5) & 63;
            int ic0 = idx & 31;
            u16 v[8];
#pragma unroll
            for (int j = 0; j < 8; ++j) {
                int ic = ic0 + j;
                float f = (ic < 20 && oc < 50) ? w2[oc * 500 + ic * 25 + tap] : 0.f;
                v[j] = f2bf(f);
            }
            *(short8*)&w2t[idx] = *(short8*)v;
        } else if (blk < 550) {
            int g = (blk - 537) * 256 + t;
            if (g >= 3200) return;
            int idx = g * 8;
            int tap = idx >> 10;
            int rem = idx & 1023;
            int oc  = rem >> 6;
            int ic0 = rem & 63;
            u16 v[8];
#pragma unroll
            for (int j = 0; j < 8; ++j) {
                int ic = ic0 + j;
                float f = (ic < 50) ? pcw[(oc * 50 + ic) * 25 + tap] : 0.f;
                v[j] = f2bf(f);
            }
            *(short8*)&w_pc[idx] = *(short8*)v;
        } else {
            for (int nn = t; nn < 512; nn += 256) {
                float bias = 0.f, wc0 = 0.f, wc1 = 0.f, f20 = 0.f, f21 = 0.f;
                if (nn < 500) {
                    bias = f1b[nn];
                    wc0  = fw[(size_t)nn * 3602 + 3600];
                    wc1  = fw[(size_t)nn * 3602 + 3601];
                    f20  = f2w[nn];
                    f21  = f2w[502 + nn];
                }
                *(float4*)&wtab[nn * 8]     = make_float4(bias, wc0, wc1, f20);
                *(float4*)&wtab[nn * 8 + 4] = make_float4(f21, 0.f, 0.f, 0.f);
            }
        }
        return;
    }

    // ---------------- conv1 branch ----------------
    u16* xbf = smem;            // 2304 shorts
    u16* im2 = smem + 2304;     // 8960 shorts [224][40]
    u16* h1s = smem + 11264;    // 8960 shorts [448][20]
    const int b = bx;

    const float* xb = x + b * 2160;
    for (int i = t; i < 2160; i += 256) {
        int r = i / 60, c = i - 60 * r;
        xbf[r * 64 + c] = f2bf(xb[i]);
    }
    __syncthreads();

    const int lane = t & 63, w = t >> 6;
    const int r16  = lane & 15;
    const int q    = lane >> 4;

    // w1 fragments built inline from float input (k = q*8+j, n = nt*16+r16)
    short8 w1f[2];
#pragma unroll
    for (int nt = 0; nt < 2; ++nt) {
        int n = nt * 16 + r16;
        union { short8 s; u16 a[8]; } wf;
#pragma unroll
        for (int j = 0; j < 8; ++j) {
            int k = q * 8 + j;
            float f = (n < 20 && k < 25) ? w1[n * 25 + k] : 0.f;
            wf.a[j] = f2bf(f);
        }
        w1f[nt] = wf.s;
    }

    const bool bact = (t < 224);
    const int lc_  = t / 112;
    const int pl_  = t - 112 * lc_;
    const int px_  = pl_ >> 2;
    const int dy_  = (pl_ & 3) >> 1, dx_ = pl_ & 1;
    const int xc_  = 2 * px_ + dx_;
    const int j0_  = xc_ >> 1;
    const int par_ = xc_ & 1;
    const int sw_  = (t >> 3) & 3;

#pragma unroll 1
    for (int g = 0; g < 8; ++g) {
        if (bact) {
            int c = 2 * g + lc_;
            u16 tap[25];
#pragma unroll
            for (int r = 0; r < 5; ++r) {
                const u32* U = (const u32*)&xbf[(2 * c + dy_ + r) * 64];
                u32 A0 = U[j0_], A1 = U[j0_ + 1], A2 = U[j0_ + 2];
                u16 e0 = par_ ? (u16)(A0 >> 16) : (u16)A0;
                u16 e1 = par_ ? (u16)A1         : (u16)(A0 >> 16);
                u16 e2 = par_ ? (u16)(A1 >> 16) : (u16)A1;
                u16 e3 = par_ ? (u16)A2         : (u16)(A1 >> 16);
                u16 e4 = par_ ? (u16)(A2 >> 16) : (u16)A2;
                tap[r * 5 + 0] = e0; tap[r * 5 + 1] = e1; tap[r * 5 + 2] = e2;
                tap[r * 5 + 3] = e3; tap[r * 5 + 4] = e4;
            }
            u32 ow[16];
#pragma unroll
            for (int j = 0; j < 12; ++j)
                ow[j] = (u32)tap[2 * j] | ((u32)tap[2 * j + 1] << 16);
            ow[12] = (u32)tap[24];
            ow[13] = 0u; ow[14] = 0u; ow[15] = 0u;
            u32* dst = (u32*)&im2[t * 40];
            *(uint4*)&dst[(0 ^ sw_) * 4] = make_uint4(ow[0],  ow[1],  ow[2],  ow[3]);
            *(uint4*)&dst[(1 ^ sw_) * 4] = make_uint4(ow[4],  ow[5],  ow[6],  ow[7]);
            *(uint4*)&dst[(2 ^ sw_) * 4] = make_uint4(ow[8],  ow[9],  ow[10], ow[11]);
            *(uint4*)&dst[(3 ^ sw_) * 4] = make_uint4(ow[12], ow[13], ow[14], ow[15]);
        }
        __syncthreads();
#pragma unroll
        for (int mi = 0; mi < 4; ++mi) {
            int mt = w + 4 * mi;
            if (mt < 14) {
                int m  = mt * 16 + r16;
                int sr = (m >> 3) & 3;
                short8 af = *(const short8*)&im2[m * 40 + ((q ^ sr) * 8)];
                floatx4 a1[2] = {};
#pragma unroll
                for (int nt = 0; nt < 2; ++nt)
                    a1[nt] = __builtin_amdgcn_mfma_f32_16x16x32_bf16(
                        af, w1f[nt], a1[nt], 0, 0, 0);
                int ci  = mt / 7;
                int mtl = mt - 7 * ci;
                int c   = 2 * g + ci;
                int pq  = mtl * 4 + q;
#pragma unroll
                for (int nt = 0; nt < 2; ++nt) {
                    int oc = nt * 16 + r16;
                    if (oc < 20) {
                        floatx4 a = a1[nt];
                        float v = fmaxf(fmaxf(a[0], a[1]), fmaxf(a[2], a[3]))
                                + b1[oc];
                        h1s[(c * 28 + pq) * 20 + oc] = f2bf(v);
                    }
                }
            }
        }
        __syncthreads();
    }

    u32* hg = h1g + (size_t)b * 4480;
    for (int i = t; i < 4480; i += 256) hg[i] = ((u32*)h1s)[i];
}

// ---------- Kernel 1b: conv2 + pool + pack + pcaps + routing ---------------
// LDS 35840 B: conv phase h1t[448][40]@0; post: hsbuf[176][72]@0;
// psum f32 overlays; pri @21760 B
__global__ __launch_bounds__(256, 4) void k_conv2p(
    const u32* __restrict__ h1g, const u16* __restrict__ w2t,
    const float* __restrict__ b2, const u16* __restrict__ w_pc,
    const float* __restrict__ pcb, const float* __restrict__ rw,
    u32* __restrict__ h_bf, float* __restrict__ cbuf)
{
    __shared__ __align__(16) u16 smem[17920];   // 35840 B
    u16* h1t = smem;

    const int t = threadIdx.x;
    const int b = blockIdx.x;

    {
        const u32* hg = h1g + (size_t)b * 4480;
#pragma unroll 1
        for (int r0 = t; r0 < 448; r0 += 256) {
            const u32* src = hg + r0 * 10;
            u32* dstp = (u32*)h1t + r0 * 20;
            uint2 a0 = *(const uint2*)(src);
            uint2 a1 = *(const uint2*)(src + 2);
            uint2 a2 = *(const uint2*)(src + 4);
            uint2 a3 = *(const uint2*)(src + 6);
            uint2 a4 = *(const uint2*)(src + 8);
            *(uint4*)(dstp)      = make_uint4(a0.x, a0.y, a1.x, a1.y);
            *(uint4*)(dstp + 4)  = make_uint4(a2.x, a2.y, a3.x, a3.y);
            *(uint2*)(dstp + 8)  = a4;
            *(uint4*)(dstp + 10) = make_uint4(0u, 0u, 0u, 0u);
            *(uint2*)(dstp + 14) = make_uint2(0u, 0u);
        }
    }
    __syncthreads();

    const int lane = t & 63, w = t >> 6;
    const int r16  = lane & 15;
    const int q    = lane >> 4;

    int abase[5];
#pragma unroll
    for (int i = 0; i < 5; ++i) {
        int mt = w + 4 * i;
        if (mt < 18) {
            int m  = mt * 16 + r16;
            int pq = m >> 2, sub = m & 3;
            int py = pq / 12, px = pq - py * 12;
            int yy = py * 2 + (sub >> 1);
            int xx = px * 2 + (sub & 1);
            abase[i] = (yy * 28 + xx) * 40 + q * 8;
        } else abase[i] = 0;
    }
    floatx4 acc2[5][4] = {};
    const u16* wtb = w2t + r16 * 32 + q * 8;

    short8 bf[4];
#pragma unroll
    for (int nt = 0; nt < 4; ++nt)
        bf[nt] = *(const short8*)&wtb[nt * 512];

#pragma unroll 1
    for (int tap = 0; tap < 25; ++tap) {
        short8 bfn[4];
        if (tap < 24) {
#pragma unroll
            for (int nt = 0; nt < 4; ++nt)
                bfn[nt] = *(const short8*)&wtb[(tap + 1) * 2048 + nt * 512];
        }
        int r = tap / 5, s = tap - 5 * r;
        int aoff = r * 1120 + s * 40;
#pragma unroll
        for (int i = 0; i < 5; ++i) {
            int mt = w + 4 * i;
            if (mt < 18) {
                short8 af = *(const short8*)&h1t[abase[i] + aoff];
#pragma unroll
                for (int nt = 0; nt < 4; ++nt)
                    acc2[i][nt] = __builtin_amdgcn_mfma_f32_16x16x32_bf16(
                        af, bf[nt], acc2[i][nt], 0, 0, 0);
            }
        }
#pragma unroll
        for (int nt = 0; nt < 4; ++nt) bf[nt] = bfn[nt];
    }
    __syncthreads();

    for (int i = t; i < 6336; i += 256) ((u32*)smem)[i] = 0u;
    __syncthreads();

    u16* hsbuf = smem;
#pragma unroll
    for (int i = 0; i < 5; ++i) {
        int mt = w + 4 * i;
        if (mt < 18) {
            int pq = mt * 4 + q;
            int ph = pq / 12, pw = pq - 12 * ph;
#pragma unroll
            for (int nt = 0; nt < 4; ++nt) {
                int oc = nt * 16 + r16;
                if (oc < 50) {
                    floatx4 a = acc2[i][nt];
                    float v = fmaxf(fmaxf(a[0], a[1]), fmaxf(a[2], a[3])) + b2[oc];
                    hsbuf[((ph + 2) * 16 + pw + 2) * 72 + oc] = f2bf(v);
                }
            }
        }
    }
    __syncthreads();

    u32* ho = h_bf + (size_t)b * 1856;
    for (int i = t; i < 1856; i += 256) {
        u32 pk = 0u;
        if (i < 1800) {
            int k2 = 2 * i;
            int pos = k2 / 50;
            int oc  = k2 - 50 * pos;
            int ph  = pos / 12, pw = pos - 12 * ph;
            pk = ((const u32*)hsbuf)[((((ph + 2) * 16) + pw + 2) * 72 + oc) >> 1];
        }
        ho[i] = pk;
    }

    int pbase[5];
#pragma unroll
    for (int mt = 0; mt < 5; ++mt) {
        int m  = mt * 16 + r16;
        int ph = m / 12, pw = m - 12 * ph;
        pbase[mt] = (ph * 16 + pw) * 72 + q * 8;
    }
    floatx4 pacc[5] = {};
    const u16* wp = w_pc + r16 * 64 + q * 8;
    const int ntap = (28 - w) >> 2;
#pragma unroll 1
    for (int tt = 0; tt < ntap; ++tt) {
        int tap = w + 4 * tt;
        short8 b0 = *(const short8*)&wp[tap * 1024];
        short8 b1 = *(const short8*)&wp[tap * 1024 + 32];
        int r = tap / 5, s = tap - 5 * r;
        int aoff = (r * 16 + s) * 72;
#pragma unroll
        for (int mt = 0; mt < 5; ++mt) {
            short8 a0 = *(const short8*)&hsbuf[pbase[mt] + aoff];
            short8 a1 = *(const short8*)&hsbuf[pbase[mt] + aoff + 32];
            pacc[mt] = __builtin_amdgcn_mfma_f32_16x16x32_bf16(a0, b0, pacc[mt], 0, 0, 0);
            pacc[mt] = __builtin_amdgcn_mfma_f32_16x16x32_bf16(a1, b1, pacc[mt], 0, 0, 0);
        }
    }
    __syncthreads();

    float* psum = (float*)smem;  // [4][80*17] f32
#pragma unroll
    for (int mt = 0; mt < 5; ++mt)
#pragma unroll
        for (int i = 0; i < 4; ++i) {
            int m = mt * 16 + q * 4 + i;
            psum[w * 1360 + m * 17 + r16] = pacc[mt][i];
        }
    __syncthreads();

    for (int i = t; i < 1152; i += 256) {
        int m = i >> 4, oc = i & 15;
        int a = m * 17 + oc;
        float s = psum[a] + psum[1360 + a] + psum[2720 + a] + psum[4080 + a]
                + pcb[oc];
        psum[a] = s;
    }
    __syncthreads();

    float* pri = (float*)(smem + 10880);
    for (int r = t; r < 288; r += 256) {
        int sub = r / 72;
        int pos = r - sub * 72;
        float u0 = psum[pos * 17 + 0  + sub];
        float u1 = psum[pos * 17 + 4  + sub];
        float u2 = psum[pos * 17 + 8  + sub];
        float u3 = psum[pos * 17 + 12 + sub];
        float n2 = u0 * u0 + u1 * u1 + u2 * u2 + u3 * u3;
        float scale = (n2 / (1.0f + n2)) * rsqrtf(n2);
        u0 *= scale; u1 *= scale; u2 *= scale; u3 *= scale;
#pragma unroll
        for (int k = 0; k < 2; ++k) {
            const float4 wv = *(const float4*)&rw[(k * 288 + r) * 4];
            pri[k * 288 + r] = u0 * wv.x + u1 * wv.y + u2 * wv.z + u3 * wv.w;
        }
    }
    __syncthreads();

    if (w < 2) {
        const float* pr = &pri[w * 288];
        float p[5];
        bool  val[5];
#pragma unroll
        for (int j = 0; j < 5; ++j) {
            int r  = j * 64 + lane;
            val[j] = r < 288;
            p[j]   = val[j] ? pr[r] : 0.0f;
        }
        float tot = wave_sum(p[0] + p[1] + p[2] + p[3] + p[4]);
        float s = tot * (1.0f / 288.0f);
        float a = s * fabsf(s) / (1.0f + s * s);
#pragma unroll
        for (int it = 0; it < 2; ++it) {
            float l[5];
            float lm = -INFINITY;
#pragma unroll
            for (int j = 0; j < 5; ++j) {
                l[j] = val[j] ? p[j] * a : -INFINITY;
                lm   = fmaxf(lm, l[j]);
            }
            lm = wave_max(lm);
            float se = 0.f, sp = 0.f;
#pragma unroll
            for (int j = 0; j < 5; ++j) {
                float e = val[j] ? expf(l[j] - lm) : 0.f;
                se += e;
                sp += e * p[j];
            }
            se = wave_sum(se);
            sp = wave_sum(sp);
            float sv = sp / se;
            float v  = sv * fabsf(sv) / (1.0f + sv * sv);
            if (it == 0) a += v;
            else if (lane == 0) cbuf[b * 2 + w] = v;
        }
    }
}

// ---------- Kernel 2: fc1 partial GEMM (m-split, GLD staging) --------------
__global__ __launch_bounds__(256) void k_fc1(
    const u16* __restrict__ h_bf, const u16* __restrict__ w_bf,
    float* __restrict__ f1buf)
{
    __shared__ __align__(16) u16 As[64 * 32];    // 4096 B
    __shared__ __align__(16) u16 Bs[64 * 32];    // 4096 B
    const int t = threadIdx.x;
    const int lane = t & 63, w = t >> 6;
    const int m0 = blockIdx.x * 64;
    const int n0 = blockIdx.y * 64;
    const int s  = blockIdx.z;
    const int k0 = s * 928;

    const u16* ga = h_bf + (size_t)(m0 + (t >> 2)) * KP + k0 + (t & 3) * 8;
    const u16* gb = w_bf + (size_t)(n0 + (t >> 2)) * KP + k0 + (t & 3) * 8;
    u16* lA = As + w * 512;
    u16* lB = Bs + w * 512;

    const int r16 = lane & 15, q = lane >> 4;
    const int ar = (w * 16 + r16) * 32 + q * 8;
    const int br = r16 * 32 + q * 8;

    floatx4 acc[4] = {};
#pragma unroll 1
    for (int it = 0; it < 29; ++it) {
        const int ko = it * 32;
        GLD(ga + ko, lA);
        GLD(gb + ko, lB);
        __syncthreads();
        short8 af = *(const short8*)&As[ar];
#pragma unroll
        for (int nt = 0; nt < 4; ++nt) {
            short8 bfv = *(const short8*)&Bs[br + nt * 512];
            acc[nt] = __builtin_amdgcn_mfma_f32_16x16x32_bf16(af, bfv, acc[nt], 0, 0, 0);
        }
        __syncthreads();
    }

    float* fo = f1buf + (size_t)s * (2048 * 512);
    const int mb = m0 + w * 16;
#pragma unroll
    for (int nt = 0; nt < 4; ++nt) {
        int n = n0 + nt * 16 + r16;
#pragma unroll
        for (int i = 0; i < 4; ++i) {
            int m = mb + q * 4 + i;
            fo[(size_t)m * 512 + n] = acc[nt][i];
        }
    }
}

// ---------- Kernel 3: fc2 final — sum partials, relu, dot ------------------
__global__ __launch_bounds__(256) void k_fc2(
    const float* __restrict__ f1buf, const float* __restrict__ wtab,
    const float* __restrict__ cc, const float* __restrict__ y,
    const float* __restrict__ f2w, const float* __restrict__ f2b,
    float* __restrict__ out)
{
    const int b = blockIdx.x * 4 + (threadIdx.x >> 6);
    const int lane = threadIdx.x & 63;
    const float* fb = f1buf + (size_t)b * 512;
    const float c0 = cc[b * 2], c1 = cc[b * 2 + 1];
    float s0 = 0.f, s1 = 0.f;
#pragma unroll
    for (int j = 0; j < 8; ++j) {
        int n = lane + j * 64;
        float raw = fb[n] + fb[1048576 + n] + fb[2097152 + n] + fb[3145728 + n];
        float4 t0 = *(const float4*)&wtab[n * 8];
        float  f21 = wtab[n * 8 + 4];
        float v = fmaxf(raw + t0.x + c0 * t0.y + c1 * t0.z, 0.f);
        s0 += v * t0.w;
        s1 += v * f21;
    }
    s0 = wave_sum(s0);
    s1 = wave_sum(s1);
    if (lane == 0) {
        float y0 = y[b * 2], y1 = y[b * 2 + 1];
        out[b * 2]     = s0 + f2b[0] + y0 * f2w[500] + y1 * f2w[501];
        out[b * 2 + 1] = s1 + f2b[1] + y0 * f2w[1002] + y1 * f2w[1003];
    }
}

// ---------------------------------------------------------------------------
extern "C" void kernel_launch(void* const* d_in, const int* in_sizes, int n_in,
                              void* d_out, int out_size, void* d_ws, size_t ws_size,
                              hipStream_t stream) {
    const float* x    = (const float*)d_in[0];
    const float* y    = (const float*)d_in[1];
    const float* c1w  = (const float*)d_in[2];
    const float* c1b  = (const float*)d_in[3];
    const float* c2w  = (const float*)d_in[4];
    const float* c2b  = (const float*)d_in[5];
    const float* pcw  = (const float*)d_in[6];
    const float* pcb  = (const float*)d_in[7];
    const float* rw   = (const float*)d_in[8];
    const float* f1w  = (const float*)d_in[9];
    const float* f1b  = (const float*)d_in[10];
    const float* f2w  = (const float*)d_in[11];
    const float* f2b  = (const float*)d_in[12];
    float* out = (float*)d_out;

    // workspace layout (~56 MB peak; h1g overlaps f1buf — h1g fully consumed
    // by k_conv2p before k_fc1 writes f1buf, stream-ordered)
    u32*   h_bf  = (u32*)d_ws;                            // 2048*1856 u32
    u16*   w_bf  = (u16*)(h_bf + (size_t)BATCH * 1856);   // 512*3712 u16
    u16*   w2t   = w_bf + (size_t)512 * KP;               // 25*64*32 u16
    u16*   w_pc  = w2t + 51200;                           // 25*16*64 u16
    float* cbuf  = (float*)(w_pc + 25600);                // 4096 f32
    float* wtab  = cbuf + 4096;                           // 4096 f32
    float* f1buf = wtab + 4096;                           // 4*2048*512 f32
    u32*   h1g   = (u32*)f1buf;                           // 2048*4480 u32 (overlap)

    k_conv1<<<BATCH + NPREP, 256, 0, stream>>>(
        x, c1w, c1b, h1g, f1w, w_bf, c2w, w2t, pcw, w_pc, f1b, f2w, wtab);
    k_conv2p<<<BATCH, 256, 0, stream>>>(h1g, w2t, c2b, w_pc, pcb, rw,
                                        h_bf, cbuf);
    dim3 g4(32, 8, 4);
    k_fc1<<<g4, 256, 0, stream>>>((const u16*)h_bf, w_bf, f1buf);
    k_fc2<<<BATCH / 4, 256, 0, stream>>>(f1buf, wtab, cbuf, y, f2w, f2b, out);
}